// Round 2
// baseline (1721.221 us; speedup 1.0000x reference)
//
#include <hip/hip_runtime.h>
#include <hip/hip_bf16.h>

#define SEQ   2048
#define DM    1024
#define NH    16
#define DK    64
#define BATCH 2
#define M_TOT (BATCH * SEQ)   // 4096

// ---------------------------------------------------------------------------
// Tiled fp32 GEMM:  Y = X @ W + bias
//   X: [M_TOT][DM] f32 row-major, W: [DM][DM] f32 row-major, bias: [DM] f32
//   head_layout=1: write Y[((b*NH+h)*SEQ + s)*DK + d]  (head-major for attention)
//   head_layout=0: write Y[m*DM + n]                   (row-major)
// Tile: BM=BN=64, BK=32; 256 threads; each thread owns a 4x4 micro-tile.
// A is stored k-major ([k][m]) in LDS so both fragments are contiguous.
// ---------------------------------------------------------------------------
__global__ __launch_bounds__(256) void proj_gemm(
    const float* __restrict__ X, const float* __restrict__ W,
    const float* __restrict__ bias, float* __restrict__ Y, int head_layout)
{
    __shared__ float At[32][65];   // [k][m], padded
    __shared__ float Bs[32][64];   // [k][n]

    const int t  = threadIdx.x;
    const int ty = t >> 4, tx = t & 15;
    const int m0 = blockIdx.y << 6;
    const int n0 = blockIdx.x << 6;

    float acc[4][4] = {};

    for (int k0 = 0; k0 < DM; k0 += 32) {
        for (int i = t; i < 64 * 32; i += 256) {
            int r = i >> 5, c = i & 31;            // r: m index, c: k index
            At[c][r] = X[(size_t)(m0 + r) * DM + k0 + c];
        }
        for (int i = t; i < 32 * 64; i += 256) {
            int r = i >> 6, c = i & 63;            // r: k index, c: n index
            Bs[r][c] = W[(size_t)(k0 + r) * DM + n0 + c];
        }
        __syncthreads();
        #pragma unroll 8
        for (int kk = 0; kk < 32; ++kk) {
            float a[4], bb[4];
            #pragma unroll
            for (int i = 0; i < 4; ++i) a[i]  = At[kk][ty * 4 + i];
            #pragma unroll
            for (int j = 0; j < 4; ++j) bb[j] = Bs[kk][tx * 4 + j];
            #pragma unroll
            for (int i = 0; i < 4; ++i)
                #pragma unroll
                for (int j = 0; j < 4; ++j)
                    acc[i][j] = fmaf(a[i], bb[j], acc[i][j]);
        }
        __syncthreads();
    }

    #pragma unroll
    for (int j = 0; j < 4; ++j) {
        float bj = bias[n0 + tx * 4 + j];
        #pragma unroll
        for (int i = 0; i < 4; ++i) acc[i][j] += bj;
    }

    #pragma unroll
    for (int i = 0; i < 4; ++i) {
        int m = m0 + ty * 4 + i;
        #pragma unroll
        for (int j = 0; j < 4; ++j) {
            int n = n0 + tx * 4 + j;
            size_t idx;
            if (head_layout) {
                int b_ = m >> 11, s = m & (SEQ - 1);
                int h  = n >> 6,  d = n & 63;
                idx = ((size_t)(b_ * NH + h) * SEQ + s) * DK + d;
            } else {
                idx = (size_t)m * DM + n;
            }
            Y[idx] = acc[i][j];
        }
    }
}

// ---------------------------------------------------------------------------
// Flash-style attention (online softmax, no SxS materialization).
// Q/K/V: [B*NH][SEQ][DK] f32.  Output A: [M_TOT][DM] f32 row-major
// (row = b*SEQ+s, col = h*DK+d) so the final projection reads it like X.
// One block per (bh, 64-row q tile); 256 threads; KV streamed in 64-row tiles.
// ---------------------------------------------------------------------------
__global__ __launch_bounds__(256) void attn(
    const float* __restrict__ Qw, const float* __restrict__ Kw,
    const float* __restrict__ Vw, float* __restrict__ A)
{
    __shared__ float Qt[64][65];   // [d][q-row]   (k-major for QK^T)
    __shared__ float Kt[64][65];   // [d][k-row]
    __shared__ float Vs[64][65];   // [k-row][d]
    __shared__ float Ss[64][65];   // scores / probs, row-major
    __shared__ float m_s[64], l_s[64], alpha_s[64];
    __shared__ float red[4][64];

    const int t  = threadIdx.x;
    const int ty = t >> 4, tx = t & 15;
    const int bh = blockIdx.x;           // 0..31
    const int q0 = blockIdx.y << 6;
    const size_t base = (size_t)bh * SEQ * DK;
    const float* Qp = Qw + base + (size_t)q0 * DK;
    const float* Kp = Kw + base;
    const float* Vp = Vw + base;

    for (int i = t; i < 64 * 64; i += 256) {
        int r = i >> 6, d = i & 63;
        Qt[d][r] = Qp[r * DK + d];
    }
    if (t < 64) { m_s[t] = -1e30f; l_s[t] = 0.f; }
    float O[4][4] = {};
    __syncthreads();

    for (int kb = 0; kb < SEQ / 64; ++kb) {
        const float* Kb = Kp + kb * 64 * DK;
        const float* Vb = Vp + kb * 64 * DK;
        for (int i = t; i < 64 * 64; i += 256) {
            int r = i >> 6, d = i & 63;
            Kt[d][r] = Kb[r * DK + d];
            Vs[r][d] = Vb[r * DK + d];
        }
        __syncthreads();

        // ---- S = (Q . K^T) * 1/sqrt(DK), 4x4 per thread ----
        float acc[4][4] = {};
        #pragma unroll 8
        for (int kk = 0; kk < 64; ++kk) {
            float a[4], bb[4];
            #pragma unroll
            for (int i = 0; i < 4; ++i) a[i]  = Qt[kk][ty * 4 + i];
            #pragma unroll
            for (int j = 0; j < 4; ++j) bb[j] = Kt[kk][tx * 4 + j];
            #pragma unroll
            for (int i = 0; i < 4; ++i)
                #pragma unroll
                for (int j = 0; j < 4; ++j)
                    acc[i][j] = fmaf(a[i], bb[j], acc[i][j]);
        }
        #pragma unroll
        for (int i = 0; i < 4; ++i)
            #pragma unroll
            for (int j = 0; j < 4; ++j)
                Ss[ty * 4 + i][tx * 4 + j] = acc[i][j] * 0.125f;
        __syncthreads();

        // ---- online softmax: row max ----
        {
            int r = t & 63, p = t >> 6;
            float pm = -1e30f;
            #pragma unroll
            for (int c = 0; c < 16; ++c) pm = fmaxf(pm, Ss[r][p * 16 + c]);
            red[p][r] = pm;
        }
        __syncthreads();
        if (t < 64) {
            float mn = fmaxf(fmaxf(red[0][t], red[1][t]),
                             fmaxf(red[2][t], red[3][t]));
            mn = fmaxf(mn, m_s[t]);
            alpha_s[t] = __expf(m_s[t] - mn);
            m_s[t] = mn;
        }
        __syncthreads();

        // ---- exp + row sum ----
        {
            int r = t & 63, p = t >> 6;
            float mr = m_s[r], ps = 0.f;
            #pragma unroll
            for (int c = 0; c < 16; ++c) {
                float e = __expf(Ss[r][p * 16 + c] - mr);
                Ss[r][p * 16 + c] = e;
                ps += e;
            }
            red[p][r] = ps;
        }
        __syncthreads();
        if (t < 64)
            l_s[t] = l_s[t] * alpha_s[t]
                   + red[0][t] + red[1][t] + red[2][t] + red[3][t];

        // ---- O = alpha*O + P @ V ----
        float al[4];
        #pragma unroll
        for (int i = 0; i < 4; ++i) al[i] = alpha_s[ty * 4 + i];
        #pragma unroll
        for (int i = 0; i < 4; ++i)
            #pragma unroll
            for (int j = 0; j < 4; ++j) O[i][j] *= al[i];
        #pragma unroll 8
        for (int kk = 0; kk < 64; ++kk) {
            float p4[4], v4[4];
            #pragma unroll
            for (int i = 0; i < 4; ++i) p4[i] = Ss[ty * 4 + i][kk];
            #pragma unroll
            for (int j = 0; j < 4; ++j) v4[j] = Vs[kk][tx * 4 + j];
            #pragma unroll
            for (int i = 0; i < 4; ++i)
                #pragma unroll
                for (int j = 0; j < 4; ++j)
                    O[i][j] = fmaf(p4[i], v4[j], O[i][j]);
        }
        __syncthreads();   // publishes l_s before final read / next tile
    }

    const int b_ = bh >> 4, h = bh & 15;
    #pragma unroll
    for (int i = 0; i < 4; ++i) {
        int r = ty * 4 + i;
        float inv = 1.f / l_s[r];
        #pragma unroll
        for (int j = 0; j < 4; ++j) {
            size_t idx = (size_t)(b_ * SEQ + q0 + r) * DM + h * DK + tx * 4 + j;
            A[idx] = O[i][j] * inv;
        }
    }
}

// ---------------------------------------------------------------------------
extern "C" void kernel_launch(void* const* d_in, const int* in_sizes, int n_in,
                              void* d_out, int out_size, void* d_ws, size_t ws_size,
                              hipStream_t stream)
{
    const float* x  = (const float*)d_in[0];
    const float* Wq = (const float*)d_in[1];
    const float* bq = (const float*)d_in[2];
    const float* Wk = (const float*)d_in[3];
    const float* bk = (const float*)d_in[4];
    const float* Wv = (const float*)d_in[5];
    const float* bv = (const float*)d_in[6];
    const float* Wo = (const float*)d_in[7];
    const float* bo = (const float*)d_in[8];

    const size_t NE = (size_t)M_TOT * DM;   // 4M elements
    float* q_ws = (float*)d_ws;             // [32][2048][64] head-major
    float* k_ws = q_ws + NE;
    float* v_ws = k_ws + NE;
    float* a_ws = v_ws + NE;                // [4096][1024] row-major
    // total ws use: 4 * 4M * 4B = 67 MB

    dim3 gp(DM / 64, M_TOT / 64);           // (16, 64)
    proj_gemm<<<gp, 256, 0, stream>>>(x, Wq, bq, q_ws, 1);
    proj_gemm<<<gp, 256, 0, stream>>>(x, Wk, bk, k_ws, 1);
    proj_gemm<<<gp, 256, 0, stream>>>(x, Wv, bv, v_ws, 1);
    attn<<<dim3(BATCH * NH, SEQ / 64), 256, 0, stream>>>(q_ws, k_ws, v_ws, a_ws);
    proj_gemm<<<gp, 256, 0, stream>>>(a_ws, Wo, bo, (float*)d_out, 0);
}

// Round 3
// 294.523 us; speedup vs baseline: 5.8441x; 5.8441x over previous
//
#include <hip/hip_runtime.h>

#define SEQ   2048
#define DM    1024
#define NH    16
#define DK    64
#define BATCH 2
#define M_TOT 4096
#define ATT_STR 72   // LDS row stride (bf16 elems): 144 B, 16B-aligned, <=2-way banks

typedef __attribute__((ext_vector_type(8))) short bf16x8;
typedef __attribute__((ext_vector_type(4))) float f32x4;
typedef unsigned short u16;

__device__ inline u16 f2b(float f) {               // f32 -> bf16 bits (RNE)
    union { float f; unsigned u; } x; x.f = f;
    return (u16)((x.u + 0x7FFFu + ((x.u >> 16) & 1u)) >> 16);
}

__device__ inline void async_cp16(const u16* g, u16* l) {
    // global -> LDS direct copy, 16 B/lane; LDS dest = wave-uniform base + lane*16
    __builtin_amdgcn_global_load_lds(
        (const __attribute__((address_space(1))) unsigned int*)g,
        (__attribute__((address_space(3))) unsigned int*)l, 16, 0, 0);
}

// ---------------------------------------------------------------------------
// x [4096][1024] f32 -> bf16
// ---------------------------------------------------------------------------
__global__ __launch_bounds__(256) void cast_x(
    const float4* __restrict__ x, ushort4* __restrict__ xb)
{
    int gid = blockIdx.x * 256 + threadIdx.x;
    float4 v = x[gid];
    ushort4 o;
    o.x = f2b(v.x); o.y = f2b(v.y); o.z = f2b(v.z); o.w = f2b(v.w);
    xb[gid] = o;
}

// ---------------------------------------------------------------------------
// W [k][n] f32 -> Wt [n][k] bf16   (32x32 LDS tile transpose)
// ---------------------------------------------------------------------------
__global__ __launch_bounds__(256) void transpose_cast(
    const float* __restrict__ W, u16* __restrict__ Wt)
{
    __shared__ float tile[32][33];
    const int t = threadIdx.x;
    const int n0 = blockIdx.x << 5, k0 = blockIdx.y << 5;
    #pragma unroll
    for (int i = 0; i < 4; ++i) {
        int idx = t + (i << 8); int r = idx >> 5, c = idx & 31;
        tile[r][c] = W[(size_t)(k0 + r) * DM + n0 + c];
    }
    __syncthreads();
    #pragma unroll
    for (int i = 0; i < 4; ++i) {
        int idx = t + (i << 8); int r = idx >> 5, c = idx & 31;
        Wt[(size_t)(n0 + r) * DM + k0 + c] = f2b(tile[c][r]);
    }
}

// ---------------------------------------------------------------------------
// m97-style MFMA GEMM:  C = A @ Bt^T + bias
//   A  [M][1024] bf16 row-major, Bt [N][1024] bf16 row-major (pre-transposed W)
// mode 1 (QKV, N=3072): out0=Q [bh][s][d], out1=K [bh][s][d], out2=Vt [bh][d][s]
// mode 0 (final, N=1024): out0 = f32 [M][1024]
// 128x128 tile, BK=32, 256 thr / 4 waves (2x2), 4x4 16x16x32 MFMAs per wave.
// ---------------------------------------------------------------------------
__global__ __launch_bounds__(256) void gemm_bt(
    const u16* __restrict__ A, const u16* __restrict__ Bt, int mode,
    const float* __restrict__ bias0, const float* __restrict__ bias1,
    const float* __restrict__ bias2,
    void* __restrict__ out0, void* __restrict__ out1, void* __restrict__ out2)
{
    __shared__ u16 As[128 * 32];
    __shared__ u16 Bs[128 * 32];
    const int t = threadIdx.x, wid = t >> 6, lane = t & 63;
    const int lr = lane & 15, quad = lane >> 4;
    const int m0 = blockIdx.y << 7, n0 = blockIdx.x << 7;
    const int wm = (wid & 1) << 6, wn = (wid >> 1) << 6;
    const int rowA = lane >> 2, colA = (lane & 3) << 3;

    f32x4 acc[4][4];
    #pragma unroll
    for (int i = 0; i < 4; ++i)
        #pragma unroll
        for (int j = 0; j < 4; ++j) acc[i][j] = (f32x4){0.f, 0.f, 0.f, 0.f};

    for (int k0 = 0; k0 < DM; k0 += 32) {
        #pragma unroll
        for (int i = 0; i < 2; ++i) {
            int ch = wid * 2 + i;                       // 16-row chunk
            async_cp16(A  + (size_t)(m0 + ch * 16 + rowA) * DM + k0 + colA,
                       As + ch * 16 * 32);
            async_cp16(Bt + (size_t)(n0 + ch * 16 + rowA) * DM + k0 + colA,
                       Bs + ch * 16 * 32);
        }
        __syncthreads();   // drains global_load_lds (vmcnt 0) + publishes LDS
        bf16x8 af[4], bfr[4];
        #pragma unroll
        for (int mt = 0; mt < 4; ++mt)
            af[mt] = *(const bf16x8*)(As + (wm + 16 * mt + lr) * 32 + quad * 8);
        #pragma unroll
        for (int nt = 0; nt < 4; ++nt)
            bfr[nt] = *(const bf16x8*)(Bs + (wn + 16 * nt + lr) * 32 + quad * 8);
        #pragma unroll
        for (int mt = 0; mt < 4; ++mt)
            #pragma unroll
            for (int nt = 0; nt < 4; ++nt)
                acc[mt][nt] = __builtin_amdgcn_mfma_f32_16x16x32_bf16(
                    af[mt], bfr[nt], acc[mt][nt], 0, 0, 0);
        __syncthreads();
    }

    // epilogue; C/D layout: row = quad*4 + reg, col = lr (within 16x16 tile)
    if (mode == 1) {
        #pragma unroll
        for (int nt = 0; nt < 4; ++nt) {
            int ng = n0 + wn + 16 * nt + lr;
            int which = ng >> 10, nn = ng & 1023;
            int h = nn >> 6, d = nn & 63;
            float bv_ = (which == 0 ? bias0 : which == 1 ? bias1 : bias2)[nn];
            #pragma unroll
            for (int mt = 0; mt < 4; ++mt) {
                int mr = m0 + wm + 16 * mt + (quad << 2);
                int b = mr >> 11, s = mr & (SEQ - 1);
                f32x4 v = acc[mt][nt];
                if (which == 2) {
                    // V transposed: vt[bh][d][s], 4 consecutive s -> packed 8B
                    ushort4 pk;
                    pk.x = f2b(v.x + bv_); pk.y = f2b(v.y + bv_);
                    pk.z = f2b(v.z + bv_); pk.w = f2b(v.w + bv_);
                    *(ushort4*)((u16*)out2 +
                        ((size_t)((b * NH + h) * DK + d)) * SEQ + s) = pk;
                } else {
                    u16* dst = which ? (u16*)out1 : (u16*)out0;
                    size_t base = ((size_t)(b * NH + h) * SEQ + s) * DK + d;
                    dst[base]          = f2b(v.x + bv_);
                    dst[base + DK]     = f2b(v.y + bv_);
                    dst[base + 2 * DK] = f2b(v.z + bv_);
                    dst[base + 3 * DK] = f2b(v.w + bv_);
                }
            }
        }
    } else {
        float* O = (float*)out0;
        #pragma unroll
        for (int nt = 0; nt < 4; ++nt) {
            int ng = n0 + wn + 16 * nt + lr;
            float bv_ = bias0[ng];
            #pragma unroll
            for (int mt = 0; mt < 4; ++mt) {
                int mr = m0 + wm + 16 * mt + (quad << 2);
                f32x4 v = acc[mt][nt];
                O[(size_t)mr * DM + ng]           = v.x + bv_;
                O[(size_t)(mr + 1) * DM + ng]     = v.y + bv_;
                O[(size_t)(mr + 2) * DM + ng]     = v.z + bv_;
                O[(size_t)(mr + 3) * DM + ng]     = v.w + bv_;
            }
        }
    }
}

// ---------------------------------------------------------------------------
// Flash attention, all-MFMA. Q,K: [bh][s][64] bf16; Vt: [bh][64][s] bf16.
// Out A: [4096][1024] bf16 (row = b*SEQ+s, col = h*64+d).
// Block = (bh, 64-q-rows); 4 waves, wave w owns q-rows [16w,16w+16).
// Online softmax state in registers (replicated across each 16-lane group).
// P goes through LDS (C/D layout -> A-operand layout round-trip).
// ---------------------------------------------------------------------------
__global__ __launch_bounds__(256) void attn_mfma(
    const u16* __restrict__ Q, const u16* __restrict__ K,
    const u16* __restrict__ Vt, u16* __restrict__ A)
{
    __shared__ u16 Qs[64 * ATT_STR];
    __shared__ u16 Ks[64 * ATT_STR];
    __shared__ u16 Vs[64 * ATT_STR];
    __shared__ u16 Ps[64 * ATT_STR];

    const int t = threadIdx.x, wid = t >> 6, lane = t & 63;
    const int lr = lane & 15, quad = lane >> 4;
    const int bh = blockIdx.x, q0 = blockIdx.y << 6;
    const u16* Qb = Q  + ((size_t)bh * SEQ + q0) * DK;
    const u16* Kb = K  + (size_t)bh * SEQ * DK;
    const u16* Vb = Vt + (size_t)bh * DK * SEQ;

    // stage Q tile [64][64] once (coalesced 16B reads, balanced b128 writes)
    #pragma unroll
    for (int i = 0; i < 2; ++i) {
        int id = t + 256 * i; int r = id >> 3, c0 = (id & 7) << 3;
        *(uint4*)(Qs + r * ATT_STR + c0) = *(const uint4*)(Qb + r * DK + c0);
    }

    f32x4 O[4];
    #pragma unroll
    for (int nt = 0; nt < 4; ++nt) O[nt] = (f32x4){0.f, 0.f, 0.f, 0.f};
    float m_r[4] = {-1e30f, -1e30f, -1e30f, -1e30f};
    float l_r[4] = {0.f, 0.f, 0.f, 0.f};

    for (int kb = 0; kb < SEQ / 64; ++kb) {
        // stage K tile [kr][d] and Vt tile [d][kr]
        #pragma unroll
        for (int i = 0; i < 2; ++i) {
            int id = t + 256 * i; int r = id >> 3, c0 = (id & 7) << 3;
            *(uint4*)(Ks + r * ATT_STR + c0) =
                *(const uint4*)(Kb + (size_t)(kb * 64 + r) * DK + c0);
            *(uint4*)(Vs + r * ATT_STR + c0) =
                *(const uint4*)(Vb + (size_t)r * SEQ + kb * 64 + c0);
        }
        __syncthreads();

        // ---- S = Q K^T (m=q, n=kr, k=d) ----
        f32x4 S[4];
        #pragma unroll
        for (int nt = 0; nt < 4; ++nt) S[nt] = (f32x4){0.f, 0.f, 0.f, 0.f};
        bf16x8 aQ0 = *(const bf16x8*)(Qs + (16 * wid + lr) * ATT_STR + quad * 8);
        bf16x8 aQ1 = *(const bf16x8*)(Qs + (16 * wid + lr) * ATT_STR + 32 + quad * 8);
        #pragma unroll
        for (int nt = 0; nt < 4; ++nt) {
            bf16x8 b0 = *(const bf16x8*)(Ks + (16 * nt + lr) * ATT_STR + quad * 8);
            bf16x8 b1 = *(const bf16x8*)(Ks + (16 * nt + lr) * ATT_STR + 32 + quad * 8);
            S[nt] = __builtin_amdgcn_mfma_f32_16x16x32_bf16(aQ0, b0, S[nt], 0, 0, 0);
            S[nt] = __builtin_amdgcn_mfma_f32_16x16x32_bf16(aQ1, b1, S[nt], 0, 0, 0);
        }

        // ---- online softmax (rows = quad*4+r; cols spread over 16-lane group) --
        float p[4][4];
        #pragma unroll
        for (int r = 0; r < 4; ++r) {
            float mx = -1e30f;
            #pragma unroll
            for (int nt = 0; nt < 4; ++nt) mx = fmaxf(mx, S[nt][r] * 0.125f);
            #pragma unroll
            for (int msk = 1; msk < 16; msk <<= 1)
                mx = fmaxf(mx, __shfl_xor(mx, msk));
            float nm = fmaxf(m_r[r], mx);
            float alpha = __expf(m_r[r] - nm);
            m_r[r] = nm;
            float sum = 0.f;
            #pragma unroll
            for (int nt = 0; nt < 4; ++nt) {
                float e = __expf(S[nt][r] * 0.125f - nm);
                p[nt][r] = e; sum += e;
            }
            #pragma unroll
            for (int msk = 1; msk < 16; msk <<= 1)
                sum += __shfl_xor(sum, msk);
            l_r[r] = l_r[r] * alpha + sum;
            #pragma unroll
            for (int nt = 0; nt < 4; ++nt) O[nt][r] *= alpha;
        }
        // write P (C/D layout) to LDS as bf16
        #pragma unroll
        for (int nt = 0; nt < 4; ++nt)
            #pragma unroll
            for (int r = 0; r < 4; ++r)
                Ps[(16 * wid + (quad << 2) + r) * ATT_STR + 16 * nt + lr] =
                    f2b(p[nt][r]);
        __syncthreads();

        // ---- O += P V (m=q, n=d, k=kr) ----
        bf16x8 aP0 = *(const bf16x8*)(Ps + (16 * wid + lr) * ATT_STR + quad * 8);
        bf16x8 aP1 = *(const bf16x8*)(Ps + (16 * wid + lr) * ATT_STR + 32 + quad * 8);
        #pragma unroll
        for (int nt = 0; nt < 4; ++nt) {
            bf16x8 v0 = *(const bf16x8*)(Vs + (16 * nt + lr) * ATT_STR + quad * 8);
            bf16x8 v1 = *(const bf16x8*)(Vs + (16 * nt + lr) * ATT_STR + 32 + quad * 8);
            O[nt] = __builtin_amdgcn_mfma_f32_16x16x32_bf16(aP0, v0, O[nt], 0, 0, 0);
            O[nt] = __builtin_amdgcn_mfma_f32_16x16x32_bf16(aP1, v1, O[nt], 0, 0, 0);
        }
        __syncthreads();   // protect Ks/Vs/Ps before next iteration's staging
    }

    const int b = bh >> 4, h = bh & 15;
    #pragma unroll
    for (int r = 0; r < 4; ++r) {
        float inv = 1.f / l_r[r];
        int s = q0 + 16 * wid + (quad << 2) + r;
        #pragma unroll
        for (int nt = 0; nt < 4; ++nt)
            A[(size_t)(b * SEQ + s) * DM + h * DK + 16 * nt + lr] =
                f2b(O[nt][r] * inv);
    }
}

// ---------------------------------------------------------------------------
extern "C" void kernel_launch(void* const* d_in, const int* in_sizes, int n_in,
                              void* d_out, int out_size, void* d_ws, size_t ws_size,
                              hipStream_t stream)
{
    const float* x  = (const float*)d_in[0];
    const float* Wq = (const float*)d_in[1];
    const float* bq = (const float*)d_in[2];
    const float* Wk = (const float*)d_in[3];
    const float* bk = (const float*)d_in[4];
    const float* Wv = (const float*)d_in[5];
    const float* bv = (const float*)d_in[6];
    const float* Wo = (const float*)d_in[7];
    const float* bo = (const float*)d_in[8];

    const size_t NE = (size_t)M_TOT * DM;        // 4M elems
    u16* xb     = (u16*)d_ws;                    //  8 MB  x bf16
    u16* wt_qkv = xb + NE;                       //  6 MB  [3][1024][1024] (n,k)
    u16* wt_o   = wt_qkv + 3 * (size_t)DM * DM;  //  2 MB
    u16* q_ws   = wt_o + (size_t)DM * DM;        //  8 MB  [bh][s][d]
    u16* k_ws   = q_ws + NE;                     //  8 MB  [bh][s][d]
    u16* vt_ws  = k_ws + NE;                     //  8 MB  [bh][d][s]
    u16* a_ws   = vt_ws + NE;                    //  8 MB  [4096][1024]
    // total 48 MB

    cast_x<<<M_TOT * DM / 4 / 256, 256, 0, stream>>>((const float4*)x, (ushort4*)xb);
    transpose_cast<<<dim3(32, 32), 256, 0, stream>>>(Wq, wt_qkv);
    transpose_cast<<<dim3(32, 32), 256, 0, stream>>>(Wk, wt_qkv + (size_t)DM * DM);
    transpose_cast<<<dim3(32, 32), 256, 0, stream>>>(Wv, wt_qkv + 2 * (size_t)DM * DM);
    transpose_cast<<<dim3(32, 32), 256, 0, stream>>>(Wo, wt_o);

    // fused QKV projection: N = 3072
    gemm_bt<<<dim3(24, 32), 256, 0, stream>>>(
        xb, wt_qkv, 1, bq, bk, bv, q_ws, k_ws, vt_ws);

    attn_mfma<<<dim3(BATCH * NH, SEQ / 64), 256, 0, stream>>>(
        q_ws, k_ws, vt_ws, a_ws);

    // output projection: N = 1024, f32 out
    gemm_bt<<<dim3(8, 32), 256, 0, stream>>>(
        a_ws, wt_o, 0, bo, nullptr, nullptr, d_out, nullptr, nullptr);
}

// Round 4
// 237.056 us; speedup vs baseline: 7.2608x; 1.2424x over previous
//
#include <hip/hip_runtime.h>

#define SEQ   2048
#define DM    1024
#define NH    16
#define DK    64
#define BATCH 2
#define M_TOT 4096
#define ATT_STR 72   // LDS row stride (bf16 elems): 144 B, 16B-aligned, <=2-way banks

typedef __attribute__((ext_vector_type(8))) short bf16x8;
typedef __attribute__((ext_vector_type(4))) float f32x4;
typedef unsigned short u16;

__device__ inline u16 f2b(float f) {               // f32 -> bf16 bits (RNE)
    union { float f; unsigned u; } x; x.f = f;
    return (u16)((x.u + 0x7FFFu + ((x.u >> 16) & 1u)) >> 16);
}

__device__ inline void async_cp16(const u16* g, u16* l) {
    __builtin_amdgcn_global_load_lds(
        (const __attribute__((address_space(1))) unsigned int*)g,
        (__attribute__((address_space(3))) unsigned int*)l, 16, 0, 0);
}

// ---------------------------------------------------------------------------
// x [4096][1024] f32 -> bf16
// ---------------------------------------------------------------------------
__global__ __launch_bounds__(256) void cast_x(
    const float4* __restrict__ x, ushort4* __restrict__ xb)
{
    int gid = blockIdx.x * 256 + threadIdx.x;
    float4 v = x[gid];
    ushort4 o;
    o.x = f2b(v.x); o.y = f2b(v.y); o.z = f2b(v.z); o.w = f2b(v.w);
    xb[gid] = o;
}

// ---------------------------------------------------------------------------
// All four weights:  W [k][n] f32 -> Wt [n][k] bf16, z selects the weight.
// Destination: wt_base + z * DM*DM  (Wq,Wk,Wv,Wo contiguous).
// ---------------------------------------------------------------------------
__global__ __launch_bounds__(256) void transpose_cast4(
    const float* __restrict__ W0, const float* __restrict__ W1,
    const float* __restrict__ W2, const float* __restrict__ W3,
    u16* __restrict__ WtBase)
{
    __shared__ float tile[32][33];
    const int t = threadIdx.x;
    const int n0 = blockIdx.x << 5, k0 = blockIdx.y << 5, z = blockIdx.z;
    const float* W = (z == 0) ? W0 : (z == 1) ? W1 : (z == 2) ? W2 : W3;
    u16* Wt = WtBase + (size_t)z * DM * DM;
    #pragma unroll
    for (int i = 0; i < 4; ++i) {
        int idx = t + (i << 8); int r = idx >> 5, c = idx & 31;
        tile[r][c] = W[(size_t)(k0 + r) * DM + n0 + c];
    }
    __syncthreads();
    #pragma unroll
    for (int i = 0; i < 4; ++i) {
        int idx = t + (i << 8); int r = idx >> 5, c = idx & 31;
        Wt[(size_t)(n0 + r) * DM + k0 + c] = f2b(tile[c][r]);
    }
}

// ---------------------------------------------------------------------------
// m97-style MFMA GEMM:  C = A @ Bt^T + bias   (unchanged from round 3)
// ---------------------------------------------------------------------------
__global__ __launch_bounds__(256) void gemm_bt(
    const u16* __restrict__ A, const u16* __restrict__ Bt, int mode,
    const float* __restrict__ bias0, const float* __restrict__ bias1,
    const float* __restrict__ bias2,
    void* __restrict__ out0, void* __restrict__ out1, void* __restrict__ out2)
{
    __shared__ u16 As[128 * 32];
    __shared__ u16 Bs[128 * 32];
    const int t = threadIdx.x, wid = t >> 6, lane = t & 63;
    const int lr = lane & 15, quad = lane >> 4;
    const int m0 = blockIdx.y << 7, n0 = blockIdx.x << 7;
    const int wm = (wid & 1) << 6, wn = (wid >> 1) << 6;
    const int rowA = lane >> 2, colA = (lane & 3) << 3;

    f32x4 acc[4][4];
    #pragma unroll
    for (int i = 0; i < 4; ++i)
        #pragma unroll
        for (int j = 0; j < 4; ++j) acc[i][j] = (f32x4){0.f, 0.f, 0.f, 0.f};

    for (int k0 = 0; k0 < DM; k0 += 32) {
        #pragma unroll
        for (int i = 0; i < 2; ++i) {
            int ch = wid * 2 + i;
            async_cp16(A  + (size_t)(m0 + ch * 16 + rowA) * DM + k0 + colA,
                       As + ch * 16 * 32);
            async_cp16(Bt + (size_t)(n0 + ch * 16 + rowA) * DM + k0 + colA,
                       Bs + ch * 16 * 32);
        }
        __syncthreads();
        bf16x8 af[4], bfr[4];
        #pragma unroll
        for (int mt = 0; mt < 4; ++mt)
            af[mt] = *(const bf16x8*)(As + (wm + 16 * mt + lr) * 32 + quad * 8);
        #pragma unroll
        for (int nt = 0; nt < 4; ++nt)
            bfr[nt] = *(const bf16x8*)(Bs + (wn + 16 * nt + lr) * 32 + quad * 8);
        #pragma unroll
        for (int mt = 0; mt < 4; ++mt)
            #pragma unroll
            for (int nt = 0; nt < 4; ++nt)
                acc[mt][nt] = __builtin_amdgcn_mfma_f32_16x16x32_bf16(
                    af[mt], bfr[nt], acc[mt][nt], 0, 0, 0);
        __syncthreads();
    }

    if (mode == 1) {
        #pragma unroll
        for (int nt = 0; nt < 4; ++nt) {
            int ng = n0 + wn + 16 * nt + lr;
            int which = ng >> 10, nn = ng & 1023;
            int h = nn >> 6, d = nn & 63;
            float bv_ = (which == 0 ? bias0 : which == 1 ? bias1 : bias2)[nn];
            #pragma unroll
            for (int mt = 0; mt < 4; ++mt) {
                int mr = m0 + wm + 16 * mt + (quad << 2);
                int b = mr >> 11, s = mr & (SEQ - 1);
                f32x4 v = acc[mt][nt];
                if (which == 2) {
                    ushort4 pk;
                    pk.x = f2b(v.x + bv_); pk.y = f2b(v.y + bv_);
                    pk.z = f2b(v.z + bv_); pk.w = f2b(v.w + bv_);
                    *(ushort4*)((u16*)out2 +
                        ((size_t)((b * NH + h) * DK + d)) * SEQ + s) = pk;
                } else {
                    u16* dst = which ? (u16*)out1 : (u16*)out0;
                    size_t base = ((size_t)(b * NH + h) * SEQ + s) * DK + d;
                    dst[base]          = f2b(v.x + bv_);
                    dst[base + DK]     = f2b(v.y + bv_);
                    dst[base + 2 * DK] = f2b(v.z + bv_);
                    dst[base + 3 * DK] = f2b(v.w + bv_);
                }
            }
        }
    } else {
        float* O = (float*)out0;
        #pragma unroll
        for (int nt = 0; nt < 4; ++nt) {
            int ng = n0 + wn + 16 * nt + lr;
            float bv_ = bias0[ng];
            #pragma unroll
            for (int mt = 0; mt < 4; ++mt) {
                int mr = m0 + wm + 16 * mt + (quad << 2);
                f32x4 v = acc[mt][nt];
                O[(size_t)mr * DM + ng]       = v.x + bv_;
                O[(size_t)(mr + 1) * DM + ng] = v.y + bv_;
                O[(size_t)(mr + 2) * DM + ng] = v.z + bv_;
                O[(size_t)(mr + 3) * DM + ng] = v.w + bv_;
            }
        }
    }
}

// ---------------------------------------------------------------------------
// Flash attention, S^T formulation.
//   Q,K: [bh][s][64] bf16; Vt: [bh][64][s] bf16; out A: [4096][1024] bf16.
// Block = (bh, 64 q-rows), 4 waves; wave w owns q columns [16w,16w+16).
//   S^T = K.Q^T  (MFMA A=K, B=Q^T): C/D col = q  -> softmax is in-lane + 2 shfl.
//   O^T = V^T.P^T (A=V^T frag from Vs[d][kr], B=P^T from LDS rows [q][kr]).
// P^T LDS region is shared with the (register-hoisted) Q tile; rows are
// wave-private, so write->read needs only lgkmcnt(0), not a barrier.
// 2 barriers per K-tile.  LDS = 3 x 64 x 72 x 2B = 27.6 KB.
// ---------------------------------------------------------------------------
__global__ __launch_bounds__(256) void attn_mfma(
    const u16* __restrict__ Q, const u16* __restrict__ K,
    const u16* __restrict__ Vt, u16* __restrict__ A)
{
    __shared__ u16 QP[64 * ATT_STR];   // Q tile [q][d], later P^T [q][kr]
    __shared__ u16 Ks[64 * ATT_STR];   // [kr][d]
    __shared__ u16 Vs[64 * ATT_STR];   // [d][kr]

    const int t = threadIdx.x, wid = t >> 6, lane = t & 63;
    const int lr = lane & 15, quad = lane >> 4;
    const int bh = blockIdx.x, q0 = blockIdx.y << 6;
    const u16* Qb = Q  + ((size_t)bh * SEQ + q0) * DK;
    const u16* Kb = K  + (size_t)bh * SEQ * DK;
    const u16* Vb = Vt + (size_t)bh * DK * SEQ;

    // stage Q tile [64 q][64 d]
    #pragma unroll
    for (int i = 0; i < 2; ++i) {
        int id = t + 256 * i; int r = id >> 3, c0 = (id & 7) << 3;
        *(uint4*)(QP + r * ATT_STR + c0) = *(const uint4*)(Qb + r * DK + c0);
    }
    __syncthreads();
    // Q^T fragments (B-operand: lane lr = q, k = d = quad*8+j), loop-invariant
    bf16x8 bQ0 = *(const bf16x8*)(QP + (16 * wid + lr) * ATT_STR + quad * 8);
    bf16x8 bQ1 = *(const bf16x8*)(QP + (16 * wid + lr) * ATT_STR + 32 + quad * 8);

    f32x4 O[4];
    #pragma unroll
    for (int mt = 0; mt < 4; ++mt) O[mt] = (f32x4){0.f, 0.f, 0.f, 0.f};
    float m_r = -1e30f, l_r = 0.f;     // state for q-row q0+16*wid+lr

    for (int kb = 0; kb < SEQ / 64; ++kb) {
        // stage K tile [kr][d], V^T tile [d][kr]
        #pragma unroll
        for (int i = 0; i < 2; ++i) {
            int id = t + 256 * i; int r = id >> 3, c0 = (id & 7) << 3;
            *(uint4*)(Ks + r * ATT_STR + c0) =
                *(const uint4*)(Kb + (size_t)(kb * 64 + r) * DK + c0);
            *(uint4*)(Vs + r * ATT_STR + c0) =
                *(const uint4*)(Vb + (size_t)r * SEQ + kb * 64 + c0);
        }
        __syncthreads();                               // (a) KV published

        // ---- S^T = K.Q^T : m = kr (4 tiles), n = q (this wave), k = d ----
        f32x4 S[4];
        #pragma unroll
        for (int mt = 0; mt < 4; ++mt) {
            bf16x8 a0 = *(const bf16x8*)(Ks + (16 * mt + lr) * ATT_STR + quad * 8);
            bf16x8 a1 = *(const bf16x8*)(Ks + (16 * mt + lr) * ATT_STR + 32 + quad * 8);
            f32x4 s = (f32x4){0.f, 0.f, 0.f, 0.f};
            s = __builtin_amdgcn_mfma_f32_16x16x32_bf16(a0, bQ0, s, 0, 0, 0);
            s = __builtin_amdgcn_mfma_f32_16x16x32_bf16(a1, bQ1, s, 0, 0, 0);
            S[mt] = s;
        }

        // ---- online softmax: 16 in-lane values (kr=16mt+4quad+r), 2 shfl ----
        float mx = -1e30f;
        #pragma unroll
        for (int mt = 0; mt < 4; ++mt)
            #pragma unroll
            for (int r = 0; r < 4; ++r) mx = fmaxf(mx, S[mt][r]);
        mx = fmaxf(mx, __shfl_xor(mx, 16));
        mx = fmaxf(mx, __shfl_xor(mx, 32));
        float nm = fmaxf(m_r, 0.125f * mx);
        float alpha = __expf(m_r - nm);
        m_r = nm;
        float sum = 0.f;
        #pragma unroll
        for (int mt = 0; mt < 4; ++mt) {
            ushort4 pk;
            float e0 = __expf(fmaf(S[mt][0], 0.125f, -nm));
            float e1 = __expf(fmaf(S[mt][1], 0.125f, -nm));
            float e2 = __expf(fmaf(S[mt][2], 0.125f, -nm));
            float e3 = __expf(fmaf(S[mt][3], 0.125f, -nm));
            sum += (e0 + e1) + (e2 + e3);
            pk.x = f2b(e0); pk.y = f2b(e1); pk.z = f2b(e2); pk.w = f2b(e3);
            // P^T row q (wave-private), cols kr = 16mt+4quad+{0..3}
            *(ushort4*)(QP + (16 * wid + lr) * ATT_STR + 16 * mt + 4 * quad) = pk;
        }
        sum += __shfl_xor(sum, 16);
        sum += __shfl_xor(sum, 32);
        l_r = l_r * alpha + sum;
        #pragma unroll
        for (int mt = 0; mt < 4; ++mt) {
            O[mt][0] *= alpha; O[mt][1] *= alpha;
            O[mt][2] *= alpha; O[mt][3] *= alpha;
        }
        // in-wave LDS write->read: drain DS queue (rows are wave-private)
        asm volatile("s_waitcnt lgkmcnt(0)" ::: "memory");

        // ---- O^T += V^T.P^T : m = d (4 tiles), n = q, k = kr ----
        bf16x8 p0 = *(const bf16x8*)(QP + (16 * wid + lr) * ATT_STR + quad * 8);
        bf16x8 p1 = *(const bf16x8*)(QP + (16 * wid + lr) * ATT_STR + 32 + quad * 8);
        #pragma unroll
        for (int mt = 0; mt < 4; ++mt) {
            bf16x8 v0 = *(const bf16x8*)(Vs + (16 * mt + lr) * ATT_STR + quad * 8);
            bf16x8 v1 = *(const bf16x8*)(Vs + (16 * mt + lr) * ATT_STR + 32 + quad * 8);
            O[mt] = __builtin_amdgcn_mfma_f32_16x16x32_bf16(v0, p0, O[mt], 0, 0, 0);
            O[mt] = __builtin_amdgcn_mfma_f32_16x16x32_bf16(v1, p1, O[mt], 0, 0, 0);
        }
        __syncthreads();                               // (b) protect Ks/Vs/QP
    }

    // epilogue: lane has O^T[d = 16mt+4quad+r][q = q0+16wid+lr]
    const int b = bh >> 4, h = bh & 15;
    const int q = q0 + 16 * wid + lr;
    float inv = 1.f / l_r;
    #pragma unroll
    for (int mt = 0; mt < 4; ++mt) {
        ushort4 pk;
        pk.x = f2b(O[mt][0] * inv); pk.y = f2b(O[mt][1] * inv);
        pk.z = f2b(O[mt][2] * inv); pk.w = f2b(O[mt][3] * inv);
        *(ushort4*)(A + (size_t)(b * SEQ + q) * DM + h * DK + 16 * mt + 4 * quad) = pk;
    }
}

// ---------------------------------------------------------------------------
extern "C" void kernel_launch(void* const* d_in, const int* in_sizes, int n_in,
                              void* d_out, int out_size, void* d_ws, size_t ws_size,
                              hipStream_t stream)
{
    const float* x  = (const float*)d_in[0];
    const float* Wq = (const float*)d_in[1];
    const float* bq = (const float*)d_in[2];
    const float* Wk = (const float*)d_in[3];
    const float* bk = (const float*)d_in[4];
    const float* Wv = (const float*)d_in[5];
    const float* bv = (const float*)d_in[6];
    const float* Wo = (const float*)d_in[7];
    const float* bo = (const float*)d_in[8];

    const size_t NE = (size_t)M_TOT * DM;        // 4M elems
    u16* xb     = (u16*)d_ws;                    //  8 MB  x bf16
    u16* wt_qkv = xb + NE;                       //  6 MB  [3][1024][1024] (n,k)
    u16* wt_o   = wt_qkv + 3 * (size_t)DM * DM;  //  2 MB  (contiguous with qkv)
    u16* q_ws   = wt_o + (size_t)DM * DM;        //  8 MB  [bh][s][d]
    u16* k_ws   = q_ws + NE;                     //  8 MB  [bh][s][d]
    u16* vt_ws  = k_ws + NE;                     //  8 MB  [bh][d][s]
    u16* a_ws   = vt_ws + NE;                    //  8 MB  [4096][1024]

    cast_x<<<M_TOT * DM / 4 / 256, 256, 0, stream>>>((const float4*)x, (ushort4*)xb);
    transpose_cast4<<<dim3(32, 32, 4), 256, 0, stream>>>(Wq, Wk, Wv, Wo, wt_qkv);

    gemm_bt<<<dim3(24, 32), 256, 0, stream>>>(
        xb, wt_qkv, 1, bq, bk, bv, q_ws, k_ws, vt_ws);

    attn_mfma<<<dim3(BATCH * NH, SEQ / 64), 256, 0, stream>>>(
        q_ws, k_ws, vt_ws, a_ws);

    gemm_bt<<<dim3(8, 32), 256, 0, stream>>>(
        a_ws, wt_o, 0, bo, nullptr, nullptr, d_out, nullptr, nullptr);
}